// Round 1
// baseline (225.303 us; speedup 1.0000x reference)
//
#include <hip/hip_runtime.h>

#define NB 64
#define ZDIM 128
#define NCOEF 1025
#define NFR 128
#define COLS 131200          /* NCOEF*NFR */
#define WINSZ 2048
#define HALFW 1024
#define NSAMP 131072
#define IMPN 4096

// workspace layout in floats
#define TF_OFF   0
#define TF_SZ    (NB*COLS)                  /* 8,396,800 */
#define CUR_OFF  (TF_OFF + TF_SZ)
#define CUR_SZ   (NB*4*NCOEF*2)             /* 524,800 */
#define SPEC_OFF (CUR_OFF + CUR_SZ)
#define SPEC_SZ  (NB*NFR*NCOEF*2)           /* 16,793,600 */
#define WINT_OFF (SPEC_OFF + SPEC_SZ)
#define WINT_SZ  (WINSZ)
#define TW_OFF   (WINT_OFF + WINT_SZ)
#define TW_SZ    (HALFW*2)

// ---------------------------------------------------------------- init tables
__global__ __launch_bounds__(256) void init_tables(float* __restrict__ winT,
                                                   float2* __restrict__ twG) {
  int i = blockIdx.x * 256 + threadIdx.x;
  if (i < WINSZ) {
    // periodic hann
    winT[i] = 0.5f - 0.5f * cosf((float)(2.0 * 3.14159265358979323846 / 2048.0) * (float)i);
  }
  if (i < HALFW) {
    // forward twiddle e^{-2*pi*i*m/2048}
    float ang = (float)(-2.0 * 3.14159265358979323846 / 2048.0) * (float)i;
    float sv, cv;
    sincosf(ang, &sv, &cv);
    twG[i] = make_float2(cv, sv);
  }
}

// ---------------------------------------------------------------- GEMM + squash
// tf[b][k*128+f] = 0.02 + sigmoid(z[b,:] . W[:, k*128+f] + bias) * 0.9702
__global__ __launch_bounds__(256) void tf_gemm_kernel(const float* __restrict__ z,
                                                      const float* __restrict__ W,
                                                      const float* __restrict__ bias,
                                                      float* __restrict__ tf) {
  __shared__ float4 zs[NB * (ZDIM / 4)];  // 64*32 float4 = 32 KB
  int tid = threadIdx.x;
  for (int i = tid; i < NB * (ZDIM / 4); i += 256)
    zs[i] = reinterpret_cast<const float4*>(z)[i];
  __syncthreads();

  int col = blockIdx.x * 256 + tid;
  if (col >= COLS) return;

  float bv = bias[col];
  float acc[NB];
#pragma unroll
  for (int b = 0; b < NB; ++b) acc[b] = bv;

  for (int zq = 0; zq < ZDIM / 4; ++zq) {
    float w0 = W[(size_t)(4 * zq + 0) * COLS + col];
    float w1 = W[(size_t)(4 * zq + 1) * COLS + col];
    float w2 = W[(size_t)(4 * zq + 2) * COLS + col];
    float w3 = W[(size_t)(4 * zq + 3) * COLS + col];
#pragma unroll
    for (int b = 0; b < NB; ++b) {
      float4 zv = zs[b * (ZDIM / 4) + zq];
      acc[b] = fmaf(zv.x, w0, fmaf(zv.y, w1, fmaf(zv.z, w2, fmaf(zv.w, w3, acc[b]))));
    }
  }

  const float RESR = (1.0f - 0.02f) * 0.99f;
#pragma unroll
  for (int b = 0; b < NB; ++b) {
    float sg = 1.0f / (1.0f + __expf(-acc[b]));
    tf[(size_t)b * COLS + col] = 0.02f + sg * RESR;
  }
}

// ---------------------------------------------------------------- FFT core
// Stockham radix-2, 2048-pt complex, 256 threads, separate re/im LDS planes.
// Natural-order in and out. tw[m] = e^{-2*pi*i*m/2048} (forward).
static __device__ __forceinline__ void wg_fft2048(float* ar, float* ai,
                                                  float* br, float* bi,
                                                  const float2* tw, bool inverse,
                                                  float** outr, float** outi) {
  float *xr = ar, *xi = ai, *yr = br, *yi = bi;
  int m = 1;
  for (int s = 0; s < 11; ++s) {
    __syncthreads();
#pragma unroll
    for (int it = 0; it < 4; ++it) {
      int t = (int)threadIdx.x + it * 256;
      int jm = t & ~(m - 1);
      float x0r = xr[t], x0i = xi[t];
      float x1r = xr[t + 1024], x1i = xi[t + 1024];
      float2 w = tw[jm];
      float wy = inverse ? -w.y : w.y;
      float sr = x0r + x1r, si = x0i + x1i;
      float dr = x0r - x1r, di = x0i - x1i;
      float pr = dr * w.x - di * wy;
      float pi = dr * wy + di * w.x;
      yr[t + jm] = sr;      yi[t + jm] = si;
      yr[t + jm + m] = pr;  yi[t + jm + m] = pi;
    }
    float* t0 = xr; xr = yr; yr = t0;
    float* t1 = xi; xi = yi; yi = t1;
    m <<= 1;
  }
  __syncthreads();
  *outr = xr; *outi = xi;
}

// ---------------------------------------------------------------- forward rfft
// grid = NB*4 (b, frame f<4). cur[(b*4+f)*1025 + k] = rfft(win * x_frame)[k]
__global__ __launch_bounds__(256) void fwd_fft_kernel(const float* __restrict__ imp,
                                                      const float* __restrict__ winT,
                                                      const float2* __restrict__ twG,
                                                      float2* __restrict__ cur) {
  __shared__ float b0r[WINSZ], b0i[WINSZ], b1r[WINSZ], b1i[WINSZ];
  __shared__ float2 tw[HALFW];
  int wg = blockIdx.x;
  int b = wg >> 2, f = wg & 3;
  int tid = threadIdx.x;

  for (int i = tid; i < HALFW; i += 256) tw[i] = twG[i];
  for (int w = tid; w < WINSZ; w += 256) {
    int s = f * HALFW + w;
    float v = (s < IMPN) ? imp[(size_t)b * IMPN + s] * winT[w] : 0.0f;
    b0r[w] = v;
    b0i[w] = 0.0f;
  }
  float *rr, *ri;
  wg_fft2048(b0r, b0i, b1r, b1i, tw, false, &rr, &ri);
  for (int k = tid; k < NCOEF; k += 256)
    cur[(size_t)wg * NCOEF + k] = make_float2(rr[k], ri[k]);
}

// ---------------------------------------------------------------- recurrence
// One thread per (b,k) chain; 128 sequential frames in spectral domain.
__global__ __launch_bounds__(256) void recur_kernel(const float* __restrict__ tf,
                                                    const float2* __restrict__ cur,
                                                    float2* __restrict__ spec) {
  int id = blockIdx.x * 256 + threadIdx.x;
  if (id >= NB * NCOEF) return;
  int b = id / NCOEF;
  int k = id - b * NCOEF;

  float g = 3.14159265358979323846f * (float)k / 1024.0f;
  float sg, cg;
  sincosf(g, &sg, &cg);
  bool herm = (k == 0) || (k == HALFW);

  const float* tfr = tf + (size_t)b * COLS + (size_t)k * NFR;
  const float2* curb = cur + (size_t)b * 4 * NCOEF + k;
  float2* specb = spec + (size_t)b * NFR * NCOEF + k;

  float pre = 0.0f, pim = 0.0f;
  for (int f = 0; f < NFR; ++f) {
    float tfv = tfr[f];
    float cr = 0.0f, ci = 0.0f;
    if (f < 4) {
      float2 cv = curb[(size_t)f * NCOEF];
      cr = cv.x; ci = cv.y;
    }
    float ire = herm ? 0.0f : pim;
    // rot = (re*c + im*s, -(re*s + im*c))
    float rre = fmaf(pre, cg, ire * sg);
    float rim = -fmaf(pre, sg, ire * cg);
    float sre = (cr + rre) * tfv;
    float sim = (ci + rim) * tfv;
    specb[(size_t)f * NCOEF] = make_float2(sre, sim);
    pre = sre; pim = sim;
  }
}

// ---------------------------------------------------------------- irfft + OLA
// grid = NB*NFR. out[b, f*1024 + t] += irfft(spec)[t] * win[t]
__global__ __launch_bounds__(256) void inv_fft_ola_kernel(const float2* __restrict__ spec,
                                                          const float* __restrict__ winT,
                                                          const float2* __restrict__ twG,
                                                          float* __restrict__ out) {
  __shared__ float b0r[WINSZ], b0i[WINSZ], b1r[WINSZ], b1i[WINSZ];
  __shared__ float2 tw[HALFW];
  int wg = blockIdx.x;
  int b = wg >> 7, f = wg & 127;
  int tid = threadIdx.x;

  for (int i = tid; i < HALFW; i += 256) tw[i] = twG[i];
  const float2* sp = spec + (size_t)wg * NCOEF;
  for (int k = tid; k < NCOEF; k += 256) {
    float2 v = sp[k];
    if (k == 0 || k == HALFW) v.y = 0.0f;  // irfft drops Im at DC/Nyquist
    b0r[k] = v.x;
    b0i[k] = v.y;
    if (k > 0 && k < HALFW) {              // Hermitian extension
      b0r[WINSZ - k] = v.x;
      b0i[WINSZ - k] = -v.y;
    }
  }
  float *rr, *ri;
  wg_fft2048(b0r, b0i, b1r, b1i, tw, true, &rr, &ri);

  const float inv_n = 1.0f / 2048.0f;
  int base = f * HALFW;
  for (int t = tid; t < WINSZ; t += 256) {
    int pos = base + t;
    if (pos < NSAMP) {
      float yv = rr[t] * inv_n * winT[t];
      atomicAdd(out + (size_t)b * NSAMP + pos, yv);
    }
  }
}

// ---------------------------------------------------------------- launch
extern "C" void kernel_launch(void* const* d_in, const int* in_sizes, int n_in,
                              void* d_out, int out_size, void* d_ws, size_t ws_size,
                              hipStream_t stream) {
  const float* z    = (const float*)d_in[0];   // 64*1*128
  const float* imp  = (const float*)d_in[1];   // 64*1*4096
  const float* W    = (const float*)d_in[2];   // 128*131200
  const float* bias = (const float*)d_in[3];   // 131200

  float* ws = (float*)d_ws;
  float*  tf   = ws + TF_OFF;
  float2* cur  = (float2*)(ws + CUR_OFF);
  float2* spec = (float2*)(ws + SPEC_OFF);
  float*  winT = ws + WINT_OFF;
  float2* twG  = (float2*)(ws + TW_OFF);
  float*  out  = (float*)d_out;

  hipMemsetAsync(out, 0, (size_t)out_size * sizeof(float), stream);

  init_tables<<<8, 256, 0, stream>>>(winT, twG);
  tf_gemm_kernel<<<(COLS + 255) / 256, 256, 0, stream>>>(z, W, bias, tf);
  fwd_fft_kernel<<<NB * 4, 256, 0, stream>>>(imp, winT, twG, cur);
  recur_kernel<<<(NB * NCOEF + 255) / 256, 256, 0, stream>>>(tf, cur, spec);
  inv_fft_ola_kernel<<<NB * NFR, 256, 0, stream>>>(spec, winT, twG, out);
}